// Round 1
// baseline (731.478 us; speedup 1.0000x reference)
//
#include <hip/hip_runtime.h>

#define N_NODES 200000
#define SDIM 128
#define VDIM 128
#define NGRAPH 512
#define EPS 1e-6f

// d_ws float layout:
// [0,512)     sum_s   (raw sum of s over node dims, segment-summed)
// [512,1024)  sum_s2
// [1024,1536) sum_v2
// [1536,2048) count
// [2048,2560) smean
// [2560,3072) inv_var
// [3072,3584) inv_vmean

// ---------------- Pass 1: per-node sums -> per-graph atomics ----------------
__global__ void eln_pass1(const float* __restrict__ s, const float* __restrict__ v,
                          const int* __restrict__ index, float* __restrict__ ws) {
    const int lane = threadIdx.x & 63;
    const int wave = (blockIdx.x * blockDim.x + threadIdx.x) >> 6;
    const int nwaves = (gridDim.x * blockDim.x) >> 6;

    for (int i = wave; i < N_NODES; i += nwaves) {
        // s: 128 contiguous floats -> 64 lanes x float2 (coalesced 512B)
        const float2* sp = reinterpret_cast<const float2*>(s + (size_t)i * SDIM);
        float2 a = sp[lane];
        float ssum  = a.x + a.y;
        float s2sum = a.x * a.x + a.y * a.y;

        // v: 384 contiguous floats -> 3 x (64 lanes x float2)
        const float2* vp = reinterpret_cast<const float2*>(v + (size_t)i * 3 * VDIM);
        float v2sum = 0.f;
#pragma unroll
        for (int c = 0; c < 3; ++c) {
            float2 b = vp[c * 64 + lane];
            v2sum += b.x * b.x + b.y * b.y;
        }

        // wave64 butterfly reduce
#pragma unroll
        for (int off = 32; off >= 1; off >>= 1) {
            ssum  += __shfl_xor(ssum,  off);
            s2sum += __shfl_xor(s2sum, off);
            v2sum += __shfl_xor(v2sum, off);
        }

        if (lane == 0) {
            int g = index[i];
            atomicAdd(ws + g,          ssum);
            atomicAdd(ws + 512 + g,    s2sum);
            atomicAdd(ws + 1024 + g,   v2sum);
            atomicAdd(ws + 1536 + g,   1.0f);
        }
    }
}

// ---------------- Stats: fold sums into smean / inv_var / inv_vmean ----------------
__global__ void eln_stats(float* __restrict__ ws) {
    int b = blockIdx.x * blockDim.x + threadIdx.x;
    if (b >= NGRAPH) return;
    float cnt = fmaxf(ws[1536 + b], 1.0f);
    float inv = 1.0f / (128.0f * cnt);      // mean over dims and nodes
    float smean = ws[b] * inv;
    float m2    = ws[512 + b] * inv;
    // var = E[mean(s^2)] - smean^2  (algebraic expansion of centered variance)
    float var   = fmaxf(m2 - smean * smean, EPS);
    float vmean = fmaxf(ws[1024 + b] * inv, EPS);
    ws[2048 + b] = smean;
    ws[2560 + b] = 1.0f / var;    // NOTE: reference divides by var, not sqrt(var)
    ws[3072 + b] = 1.0f / vmean;
}

// ---------------- Pass 2a: sout = (s - smean) * inv_var * w + b ----------------
__global__ void eln_pass2_s(const float* __restrict__ s, const int* __restrict__ index,
                            const float* __restrict__ weight, const float* __restrict__ bias,
                            const float* __restrict__ ws, float* __restrict__ out) {
    const int total4 = N_NODES * (SDIM / 4);   // 6.4M float4
    const int stride = gridDim.x * blockDim.x;
    for (int idx = blockIdx.x * blockDim.x + threadIdx.x; idx < total4; idx += stride) {
        int node = idx >> 5;        // 32 float4 per node
        int d4   = idx & 31;
        int g = index[node];
        float smean = ws[2048 + g];
        float ivar  = ws[2560 + g];
        float4 sv = reinterpret_cast<const float4*>(s)[idx];
        float4 w  = reinterpret_cast<const float4*>(weight)[d4];
        float4 bb = reinterpret_cast<const float4*>(bias)[d4];
        float4 o;
        o.x = (sv.x - smean) * ivar * w.x + bb.x;
        o.y = (sv.y - smean) * ivar * w.y + bb.y;
        o.z = (sv.z - smean) * ivar * w.z + bb.z;
        o.w = (sv.w - smean) * ivar * w.w + bb.w;
        reinterpret_cast<float4*>(out)[idx] = o;
    }
}

// ---------------- Pass 2b: vout = v * inv_vmean ----------------
__global__ void eln_pass2_v(const float* __restrict__ v, const int* __restrict__ index,
                            const float* __restrict__ ws, float* __restrict__ out) {
    const int total4 = N_NODES * (3 * VDIM / 4);   // 19.2M float4
    const int stride = gridDim.x * blockDim.x;
    for (int idx = blockIdx.x * blockDim.x + threadIdx.x; idx < total4; idx += stride) {
        int node = idx / 96;        // 96 float4 per node
        float ivm = ws[3072 + index[node]];
        float4 vv = reinterpret_cast<const float4*>(v)[idx];
        float4 o;
        o.x = vv.x * ivm;
        o.y = vv.y * ivm;
        o.z = vv.z * ivm;
        o.w = vv.w * ivm;
        reinterpret_cast<float4*>(out)[idx] = o;
    }
}

extern "C" void kernel_launch(void* const* d_in, const int* in_sizes, int n_in,
                              void* d_out, int out_size, void* d_ws, size_t ws_size,
                              hipStream_t stream) {
    const float* s      = (const float*)d_in[0];
    const float* v      = (const float*)d_in[1];
    const int*   index  = (const int*)d_in[2];
    const float* weight = (const float*)d_in[3];
    const float* bias   = (const float*)d_in[4];
    float* out = (float*)d_out;
    float* ws  = (float*)d_ws;

    hipMemsetAsync(d_ws, 0, 2048 * sizeof(float), stream);

    eln_pass1<<<2048, 256, 0, stream>>>(s, v, index, ws);
    eln_stats<<<2, 256, 0, stream>>>(ws);
    eln_pass2_s<<<2048, 256, 0, stream>>>(s, index, weight, bias, ws, out);
    eln_pass2_v<<<4096, 256, 0, stream>>>(v, index, ws, out + (size_t)N_NODES * SDIM);
}

// Round 2
// 248.672 us; speedup vs baseline: 2.9415x; 2.9415x over previous
//
#include <hip/hip_runtime.h>

#define N_NODES 200000
#define SDIM 128
#define VDIM 128
#define NGRAPH 512
#define EPS 1e-6f
#define NODES_PER_BLOCK 100   // 2000 blocks x 100 nodes = 200000

// d_ws float layout:
// [0,512)     sum_s     [512,1024)  sum_s2    [1024,1536) sum_v2   [1536,2048) count
// [2048,2560) smean     [2560,3072) inv_var   [3072,3584) inv_vmean

// ---------------- Pass 1: contiguous-chunk register accumulation ----------------
// Sorted index => graph id is block-uniform per node and changes rarely within a
// block's 100-node chunk. Accumulate in registers, flush on graph change.
__global__ void eln_pass1(const float* __restrict__ s, const float* __restrict__ v,
                          const int* __restrict__ index, float* __restrict__ ws) {
    __shared__ float redA[4], redB[4], redC[4];

    const int tid  = threadIdx.x;
    const int lane = tid & 63;
    const int wv   = tid >> 6;

    const int start = blockIdx.x * NODES_PER_BLOCK;
    const int end   = start + NODES_PER_BLOCK;   // N divides evenly

    float ssum = 0.f, s2sum = 0.f, v2sum = 0.f;
    int curG = index[start];
    int cnt  = 0;

#define FLUSH()                                                                     \
    do {                                                                            \
        float a = ssum, b = s2sum, c = v2sum;                                       \
        _Pragma("unroll")                                                           \
        for (int off = 32; off >= 1; off >>= 1) {                                   \
            a += __shfl_xor(a, off); b += __shfl_xor(b, off); c += __shfl_xor(c, off); \
        }                                                                           \
        if (lane == 0) { redA[wv] = a; redB[wv] = b; redC[wv] = c; }                \
        __syncthreads();                                                            \
        if (tid == 0) {                                                             \
            atomicAdd(ws + curG,        redA[0] + redA[1] + redA[2] + redA[3]);     \
            atomicAdd(ws + 512 + curG,  redB[0] + redB[1] + redB[2] + redB[3]);     \
            atomicAdd(ws + 1024 + curG, redC[0] + redC[1] + redC[2] + redC[3]);     \
            atomicAdd(ws + 1536 + curG, (float)cnt);                                \
        }                                                                           \
        __syncthreads();                                                            \
        ssum = 0.f; s2sum = 0.f; v2sum = 0.f;                                       \
    } while (0)

    for (int i = start; i < end; ++i) {
        int g = index[i];                 // block-uniform, L1-broadcast
        if (g != curG) {                  // uniform branch -> syncthreads safe
            FLUSH();
            curG = g;
            cnt = 0;
        }
        if (tid < 64) {
            // s row: 128 floats = 64 lanes x float2 (one coalesced 512B read)
            float2 a = reinterpret_cast<const float2*>(s + (size_t)i * SDIM)[tid];
            ssum  += a.x + a.y;
            s2sum += a.x * a.x + a.y * a.y;
        } else {
            // v row: 384 floats = 192 lanes x float2 (three coalesced 512B reads)
            float2 b = reinterpret_cast<const float2*>(v + (size_t)i * 3 * VDIM)[tid - 64];
            v2sum += b.x * b.x + b.y * b.y;
        }
        cnt++;
    }
    FLUSH();
#undef FLUSH
}

// ---------------- Stats: fold sums into smean / inv_var / inv_vmean ----------------
__global__ void eln_stats(float* __restrict__ ws) {
    int b = blockIdx.x * blockDim.x + threadIdx.x;
    if (b >= NGRAPH) return;
    float cnt = fmaxf(ws[1536 + b], 1.0f);
    float inv = 1.0f / (128.0f * cnt);      // mean over dims and nodes
    float smean = ws[b] * inv;
    float m2    = ws[512 + b] * inv;
    float var   = fmaxf(m2 - smean * smean, EPS);   // E[s^2] - E[s]^2
    float vmean = fmaxf(ws[1024 + b] * inv, EPS);
    ws[2048 + b] = smean;
    ws[2560 + b] = 1.0f / var;    // reference divides by var, not sqrt(var)
    ws[3072 + b] = 1.0f / vmean;
}

// ---------------- Pass 2a: sout = (s - smean) * inv_var * w + b ----------------
__global__ void eln_pass2_s(const float* __restrict__ s, const int* __restrict__ index,
                            const float* __restrict__ weight, const float* __restrict__ bias,
                            const float* __restrict__ ws, float* __restrict__ out) {
    const int total4 = N_NODES * (SDIM / 4);   // 6.4M float4
    const int stride = gridDim.x * blockDim.x;
    for (int idx = blockIdx.x * blockDim.x + threadIdx.x; idx < total4; idx += stride) {
        int node = idx >> 5;        // 32 float4 per node
        int d4   = idx & 31;
        int g = index[node];
        float smean = ws[2048 + g];
        float ivar  = ws[2560 + g];
        float4 sv = reinterpret_cast<const float4*>(s)[idx];
        float4 w  = reinterpret_cast<const float4*>(weight)[d4];
        float4 bb = reinterpret_cast<const float4*>(bias)[d4];
        float4 o;
        o.x = (sv.x - smean) * ivar * w.x + bb.x;
        o.y = (sv.y - smean) * ivar * w.y + bb.y;
        o.z = (sv.z - smean) * ivar * w.z + bb.z;
        o.w = (sv.w - smean) * ivar * w.w + bb.w;
        reinterpret_cast<float4*>(out)[idx] = o;
    }
}

// ---------------- Pass 2b: vout = v * inv_vmean ----------------
__global__ void eln_pass2_v(const float* __restrict__ v, const int* __restrict__ index,
                            const float* __restrict__ ws, float* __restrict__ out) {
    const int total4 = N_NODES * (3 * VDIM / 4);   // 19.2M float4
    const int stride = gridDim.x * blockDim.x;
    for (int idx = blockIdx.x * blockDim.x + threadIdx.x; idx < total4; idx += stride) {
        int node = idx / 96;        // 96 float4 per node
        float ivm = ws[3072 + index[node]];
        float4 vv = reinterpret_cast<const float4*>(v)[idx];
        float4 o;
        o.x = vv.x * ivm;
        o.y = vv.y * ivm;
        o.z = vv.z * ivm;
        o.w = vv.w * ivm;
        reinterpret_cast<float4*>(out)[idx] = o;
    }
}

extern "C" void kernel_launch(void* const* d_in, const int* in_sizes, int n_in,
                              void* d_out, int out_size, void* d_ws, size_t ws_size,
                              hipStream_t stream) {
    const float* s      = (const float*)d_in[0];
    const float* v      = (const float*)d_in[1];
    const int*   index  = (const int*)d_in[2];
    const float* weight = (const float*)d_in[3];
    const float* bias   = (const float*)d_in[4];
    float* out = (float*)d_out;
    float* ws  = (float*)d_ws;

    hipMemsetAsync(d_ws, 0, 2048 * sizeof(float), stream);

    eln_pass1<<<N_NODES / NODES_PER_BLOCK, 256, 0, stream>>>(s, v, index, ws);
    eln_stats<<<2, 256, 0, stream>>>(ws);
    eln_pass2_s<<<2048, 256, 0, stream>>>(s, index, weight, bias, ws, out);
    eln_pass2_v<<<4096, 256, 0, stream>>>(v, index, ws, out + (size_t)N_NODES * SDIM);
}

// Round 3
// 212.077 us; speedup vs baseline: 3.4491x; 1.1726x over previous
//
#include <hip/hip_runtime.h>

#define N_NODES 200000
#define SDIM 128
#define VDIM 128
#define NGRAPH 512
#define EPS 1e-6f
#define NODES_PER_WAVE 25
#define WAVES_TOTAL (N_NODES / NODES_PER_WAVE)   // 8000
#define P1_BLOCKS (WAVES_TOTAL / 4)              // 2000 blocks x 4 waves

typedef float v2f __attribute__((ext_vector_type(2)));
typedef float v4f __attribute__((ext_vector_type(4)));

// d_ws float layout:
// [0,512)     sum_s     [512,1024)  sum_s2    [1024,1536) sum_v2   [1536,2048) count
// [2048,2560) smean     [2560,3072) inv_var   [3072,3584) inv_vmean

// ---------------- Pass 1: wave-autonomous contiguous runs ----------------
// Sorted index => graph id constant over long runs. Each wave owns 25 nodes,
// accumulates per-lane in registers (32B/lane/node, 4 independent loads),
// shuffle-reduces + atomics only when the graph id changes (~1.06x per wave).
__global__ void __launch_bounds__(256) eln_pass1(const float* __restrict__ s,
                                                 const float* __restrict__ v,
                                                 const int* __restrict__ index,
                                                 float* __restrict__ ws) {
    const int lane = threadIdx.x & 63;
    const int wave = blockIdx.x * 4 + (threadIdx.x >> 6);
    const int start = wave * NODES_PER_WAVE;
    const int end   = start + NODES_PER_WAVE;

    float ssum = 0.f, s2sum = 0.f, v2sum = 0.f;
    float cnt = 0.f;
    int curG = index[start];

    auto flush = [&]() {
        float a = ssum, b = s2sum, c = v2sum;
#pragma unroll
        for (int off = 32; off >= 1; off >>= 1) {
            a += __shfl_xor(a, off);
            b += __shfl_xor(b, off);
            c += __shfl_xor(c, off);
        }
        if (lane == 0) {
            atomicAdd(ws + curG,        a);
            atomicAdd(ws + 512 + curG,  b);
            atomicAdd(ws + 1024 + curG, c);
            atomicAdd(ws + 1536 + curG, cnt);   // cnt identical across lanes
        }
        ssum = 0.f; s2sum = 0.f; v2sum = 0.f; cnt = 0.f;
    };

    for (int i = start; i < end; ++i) {
        int g = index[i];                      // wave-uniform broadcast load
        if (g != curG) { flush(); curG = g; }  // uniform branch, rare

        // s row: 128 floats = 64 lanes x float2 (coalesced 512B) — keep in L3
        v2f a = reinterpret_cast<const v2f*>(s)[(size_t)i * 64 + lane];
        // v row: 384 floats = 192 float2; lane reads 3 (coalesced) — single-use, nt
        const v2f* vp = reinterpret_cast<const v2f*>(v) + (size_t)i * 192;
        v2f b0 = __builtin_nontemporal_load(vp + lane);
        v2f b1 = __builtin_nontemporal_load(vp + 64 + lane);
        v2f b2 = __builtin_nontemporal_load(vp + 128 + lane);

        ssum  += a[0] + a[1];
        s2sum += a[0] * a[0] + a[1] * a[1];
        v2sum += b0[0] * b0[0] + b0[1] * b0[1]
               + b1[0] * b1[0] + b1[1] * b1[1]
               + b2[0] * b2[0] + b2[1] * b2[1];
        cnt += 1.f;
    }
    flush();
}

// ---------------- Stats: fold sums into smean / inv_var / inv_vmean ----------------
__global__ void eln_stats(float* __restrict__ ws) {
    int b = blockIdx.x * blockDim.x + threadIdx.x;
    if (b >= NGRAPH) return;
    float cnt = fmaxf(ws[1536 + b], 1.0f);
    float inv = 1.0f / (128.0f * cnt);              // mean over dims and nodes
    float smean = ws[b] * inv;
    float m2    = ws[512 + b] * inv;
    float var   = fmaxf(m2 - smean * smean, EPS);   // E[s^2] - E[s]^2
    float vmean = fmaxf(ws[1024 + b] * inv, EPS);
    ws[2048 + b] = smean;
    ws[2560 + b] = 1.0f / var;    // reference divides by var, not sqrt(var)
    ws[3072 + b] = 1.0f / vmean;
}

// ---------------- Pass 2 (fused): sout then vout, grid-stride ----------------
__global__ void __launch_bounds__(256) eln_pass2(const float* __restrict__ s,
                                                 const float* __restrict__ v,
                                                 const int* __restrict__ index,
                                                 const float* __restrict__ wgt,
                                                 const float* __restrict__ bias,
                                                 const float* __restrict__ ws,
                                                 float* __restrict__ out) {
    const int S4 = N_NODES * (SDIM / 4);        // 6.4M float4
    const int V4 = N_NODES * (3 * VDIM / 4);    // 19.2M float4
    const int stride = gridDim.x * blockDim.x;
    const int t0 = blockIdx.x * blockDim.x + threadIdx.x;
    float* __restrict__ outv = out + (size_t)N_NODES * SDIM;

    // s-part: reads should hit L3 (kept resident by pass1's normal s loads)
    for (int idx = t0; idx < S4; idx += stride) {
        int node = idx >> 5;                    // 32 float4 per node
        int d4   = idx & 31;
        int g = index[node];
        float smean = ws[2048 + g];
        float ivar  = ws[2560 + g];
        v4f sv = reinterpret_cast<const v4f*>(s)[idx];
        v4f w  = reinterpret_cast<const v4f*>(wgt)[d4];
        v4f bb = reinterpret_cast<const v4f*>(bias)[d4];
        v4f o  = (sv - smean) * ivar * w + bb;
        __builtin_nontemporal_store(o, reinterpret_cast<v4f*>(out) + idx);
    }

    // v-part: single-use streams, nt both ways
    for (int idx = t0; idx < V4; idx += stride) {
        int node = idx / 96;                    // 96 float4 per node
        float ivm = ws[3072 + index[node]];
        v4f vv = __builtin_nontemporal_load(reinterpret_cast<const v4f*>(v) + idx);
        v4f o  = vv * ivm;
        __builtin_nontemporal_store(o, reinterpret_cast<v4f*>(outv) + idx);
    }
}

extern "C" void kernel_launch(void* const* d_in, const int* in_sizes, int n_in,
                              void* d_out, int out_size, void* d_ws, size_t ws_size,
                              hipStream_t stream) {
    const float* s      = (const float*)d_in[0];
    const float* v      = (const float*)d_in[1];
    const int*   index  = (const int*)d_in[2];
    const float* weight = (const float*)d_in[3];
    const float* bias   = (const float*)d_in[4];
    float* out = (float*)d_out;
    float* ws  = (float*)d_ws;

    hipMemsetAsync(d_ws, 0, 2048 * sizeof(float), stream);

    eln_pass1<<<P1_BLOCKS, 256, 0, stream>>>(s, v, index, ws);
    eln_stats<<<2, 256, 0, stream>>>(ws);
    eln_pass2<<<4096, 256, 0, stream>>>(s, v, index, weight, bias, ws, out);
}

// Round 4
// 199.250 us; speedup vs baseline: 3.6712x; 1.0644x over previous
//
#include <hip/hip_runtime.h>

#define N_NODES 200000
#define SDIM 128
#define VDIM 128
#define NGRAPH 512
#define EPS 1e-6f
#define NODES_PER_WAVE 25
#define WAVES_TOTAL (N_NODES / NODES_PER_WAVE)   // 8000
#define P1_BLOCKS (WAVES_TOTAL / 4)              // 2000 blocks x 4 waves
#define P2_BLOCKS 4096

typedef float v2f __attribute__((ext_vector_type(2)));
typedef float v4f __attribute__((ext_vector_type(4)));

// d_ws float layout:
// [0,512)     sum_s     [512,1024)  sum_s2    [1024,1536) sum_v2   [1536,2048) count
// [2048,2560) smean     [2560,3072) inv_var   [3072,3584) inv_vmean

// ---------------- Pass 1: wave-autonomous contiguous runs ----------------
// Sorted index => graph id constant over long runs. Each wave owns 25 nodes.
// v is loaded NORMALLY (cached) so the v-tail is L3-resident when pass2 starts.
__global__ void __launch_bounds__(256) eln_pass1(const float* __restrict__ s,
                                                 const float* __restrict__ v,
                                                 const int* __restrict__ index,
                                                 float* __restrict__ ws) {
    const int lane = threadIdx.x & 63;
    const int wave = blockIdx.x * 4 + (threadIdx.x >> 6);
    const int start = wave * NODES_PER_WAVE;
    const int end   = start + NODES_PER_WAVE;

    float ssum = 0.f, s2sum = 0.f, v2sum = 0.f;
    float cnt = 0.f;
    int curG = index[start];

    auto flush = [&]() {
        float a = ssum, b = s2sum, c = v2sum;
#pragma unroll
        for (int off = 32; off >= 1; off >>= 1) {
            a += __shfl_xor(a, off);
            b += __shfl_xor(b, off);
            c += __shfl_xor(c, off);
        }
        if (lane == 0) {
            atomicAdd(ws + curG,        a);
            atomicAdd(ws + 512 + curG,  b);
            atomicAdd(ws + 1024 + curG, c);
            atomicAdd(ws + 1536 + curG, cnt);   // cnt identical across lanes
        }
        ssum = 0.f; s2sum = 0.f; v2sum = 0.f; cnt = 0.f;
    };

    for (int i = start; i < end; ++i) {
        int g = index[i];                      // wave-uniform broadcast load
        if (g != curG) { flush(); curG = g; }  // uniform branch, rare

        // s row: 128 floats = 64 lanes x float2 (coalesced 512B), cached -> L3
        v2f a = reinterpret_cast<const v2f*>(s)[(size_t)i * 64 + lane];
        // v row: 384 floats; cached so the tail survives in L3 for pass2
        const v2f* vp = reinterpret_cast<const v2f*>(v) + (size_t)i * 192;
        v2f b0 = vp[lane];
        v2f b1 = vp[64 + lane];
        v2f b2 = vp[128 + lane];

        ssum  += a[0] + a[1];
        s2sum += a[0] * a[0] + a[1] * a[1];
        v2sum += b0[0] * b0[0] + b0[1] * b0[1]
               + b1[0] * b1[0] + b1[1] * b1[1]
               + b2[0] * b2[0] + b2[1] * b2[1];
        cnt += 1.f;
    }
    flush();
}

// ---------------- Stats: fold sums into smean / inv_var / inv_vmean ----------------
__global__ void eln_stats(float* __restrict__ ws) {
    int b = threadIdx.x + blockIdx.x * blockDim.x;
    if (b >= NGRAPH) return;
    float cnt = fmaxf(ws[1536 + b], 1.0f);
    float inv = 1.0f / (128.0f * cnt);              // mean over dims and nodes
    float smean = ws[b] * inv;
    float m2    = ws[512 + b] * inv;
    float var   = fmaxf(m2 - smean * smean, EPS);   // E[s^2] - E[s]^2
    float vmean = fmaxf(ws[1024 + b] * inv, EPS);
    ws[2048 + b] = smean;
    ws[2560 + b] = 1.0f / var;    // reference divides by var, not sqrt(var)
    ws[3072 + b] = 1.0f / vmean;
}

// ---------------- Pass 2 (fused): sout (forward) then vout (reversed) ----------------
__global__ void __launch_bounds__(256) eln_pass2(const float* __restrict__ s,
                                                 const float* __restrict__ v,
                                                 const int* __restrict__ index,
                                                 const float* __restrict__ wgt,
                                                 const float* __restrict__ bias,
                                                 const float* __restrict__ ws,
                                                 float* __restrict__ out) {
    const int S4 = N_NODES * (SDIM / 4);        // 6.4M float4
    const int V4 = N_NODES * (3 * VDIM / 4);    // 19.2M float4
    const int stride = P2_BLOCKS * 256;
    const int t0 = blockIdx.x * blockDim.x + threadIdx.x;
    float* __restrict__ outv = out + (size_t)N_NODES * SDIM;

    // s-part: reads hit L3 (s = 102 MB, kept resident by pass1)
    for (int idx = t0; idx < S4; idx += stride) {
        int node = idx >> 5;                    // 32 float4 per node
        int d4   = idx & 31;
        int g = index[node];
        float smean = ws[2048 + g];
        float ivar  = ws[2560 + g];
        v4f sv = reinterpret_cast<const v4f*>(s)[idx];
        v4f w  = reinterpret_cast<const v4f*>(wgt)[d4];
        v4f bb = reinterpret_cast<const v4f*>(bias)[d4];
        v4f o  = (sv - smean) * ivar * w + bb;
        __builtin_nontemporal_store(o, reinterpret_cast<v4f*>(out) + idx);
    }

    // v-part: REVERSED slab order — harvest the L3-resident v-tail first.
    // nt loads probe the cache but don't allocate, so head-misses don't
    // evict s or the remaining tail. Reversal also leaves the v-head as the
    // newest L3 content for the next replay's pass1 (which reads forward).
    const int iters = (V4 + stride - 1) / stride;
    for (int it = iters - 1; it >= 0; --it) {
        int idx = it * stride + t0;
        if (idx < V4) {
            int node = idx / 96;                // 96 float4 per node
            float ivm = ws[3072 + index[node]];
            v4f vv = __builtin_nontemporal_load(reinterpret_cast<const v4f*>(v) + idx);
            v4f o  = vv * ivm;
            __builtin_nontemporal_store(o, reinterpret_cast<v4f*>(outv) + idx);
        }
    }
}

extern "C" void kernel_launch(void* const* d_in, const int* in_sizes, int n_in,
                              void* d_out, int out_size, void* d_ws, size_t ws_size,
                              hipStream_t stream) {
    const float* s      = (const float*)d_in[0];
    const float* v      = (const float*)d_in[1];
    const int*   index  = (const int*)d_in[2];
    const float* weight = (const float*)d_in[3];
    const float* bias   = (const float*)d_in[4];
    float* out = (float*)d_out;
    float* ws  = (float*)d_ws;

    hipMemsetAsync(d_ws, 0, 2048 * sizeof(float), stream);

    eln_pass1<<<P1_BLOCKS, 256, 0, stream>>>(s, v, index, ws);
    eln_stats<<<1, 512, 0, stream>>>(ws);
    eln_pass2<<<P2_BLOCKS, 256, 0, stream>>>(s, v, index, weight, bias, ws, out);
}